// Round 1
// baseline (1838.591 us; speedup 1.0000x reference)
//
#include <hip/hip_runtime.h>
#include <stdint.h>

#define NT 256

__device__ __forceinline__ unsigned fenc(float f) {
  unsigned u = __float_as_uint(f);
  return (u & 0x80000000u) ? ~u : (u | 0x80000000u);
}
__device__ __forceinline__ float fdec(unsigned u) {
  return (u & 0x80000000u) ? __uint_as_float(u & 0x7fffffffu) : __uint_as_float(~u);
}
__device__ __forceinline__ float lrelu(float x) { return x > 0.f ? x : 0.2f * x; }

// ---- edge dtype detection (int32 vs int64) + conversion ----
__global__ void detect_kernel(const int* __restrict__ ei, int* __restrict__ flag, int twoE) {
  __shared__ int any;
  if (threadIdx.x == 0) any = 0;
  __syncthreads();
  int n = twoE < 4096 ? twoE : 4096;
  for (int i = threadIdx.x * 2 + 1; i < n; i += 2 * NT)
    if (ei[i] != 0) any = 1;   // benign race, writes same value
  __syncthreads();
  if (threadIdx.x == 0) *flag = any;   // 1 -> data is int32, 0 -> int64
}

__global__ void cvt_edges_kernel(const void* __restrict__ ei, int* __restrict__ out,
                                 const int* __restrict__ flag, int twoE) {
  int i = blockIdx.x * NT + threadIdx.x;
  if (i >= twoE) return;
  if (*flag) out[i] = ((const int*)ei)[i];
  else       out[i] = (int)((const long long*)ei)[i];
}

// ---- layer 1 GEMM + attention dots: xl1 = x@W1, a1 = [a_l | a_r] ----
__global__ void __launch_bounds__(NT)
gemm1_kernel(const float* __restrict__ x, const float* __restrict__ W1,
             const float* __restrict__ attl, const float* __restrict__ attr,
             float* __restrict__ xl1, float* __restrict__ a1, int N) {
  __shared__ float Ws[128 * 64];
  __shared__ float xs[4][128];
  for (int i = threadIdx.x; i < 128 * 64; i += NT) Ws[i] = W1[i];
  int row0 = blockIdx.x * 4;
  for (int i = threadIdx.x; i < 4 * 128; i += NT) {
    int r = row0 + (i >> 7);
    xs[i >> 7][i & 127] = (r < N) ? x[r * 128 + (i & 127)] : 0.f;
  }
  __syncthreads();
  int wave = threadIdx.x >> 6;
  int lane = threadIdx.x & 63;
  float acc = 0.f;
#pragma unroll 8
  for (int k = 0; k < 128; ++k) acc += xs[wave][k] * Ws[k * 64 + lane];
  int n = row0 + wave;
  if (n < N) {
    xl1[n * 64 + lane] = acc;
    float pl = acc * attl[lane];
    float pr = acc * attr[lane];
#pragma unroll
    for (int m = 1; m < 8; m <<= 1) {
      pl += __shfl_xor(pl, m, 64);
      pr += __shfl_xor(pr, m, 64);
    }
    if ((lane & 7) == 0) {
      int h = lane >> 3;
      a1[n * 16 + h] = pl;
      a1[n * 16 + 8 + h] = pr;
    }
  }
}

// ---- init accumulator (=bias) and per-(node,head) max/denom buffers ----
__global__ void init_kernel(float* __restrict__ out, const float* __restrict__ bias,
                            unsigned* __restrict__ maxb, float* __restrict__ denom, int N) {
  int i = blockIdx.x * NT + threadIdx.x;
  if (i < N * 64) out[i] = bias[i & 63];
  if (i < N * 8) { maxb[i] = 0u; denom[i] = 0.f; }
}

// ---- segment max over dst (per head) ----
__global__ void __launch_bounds__(NT)
edge_max_kernel(const int* __restrict__ src, const int* __restrict__ dst,
                const float* __restrict__ a, unsigned* __restrict__ maxb, int E) {
  int e = blockIdx.x * NT + threadIdx.x;
  if (e >= E) return;
  int s = src[e], d = dst[e];
  const float4* pl = (const float4*)(a + s * 16);
  const float4* pr = (const float4*)(a + d * 16 + 8);
  float4 l0 = pl[0], l1 = pl[1];
  float4 r0 = pr[0], r1 = pr[1];
  float sc[8] = {l0.x + r0.x, l0.y + r0.y, l0.z + r0.z, l0.w + r0.w,
                 l1.x + r1.x, l1.y + r1.y, l1.z + r1.z, l1.w + r1.w};
  unsigned* mb = maxb + d * 8;
#pragma unroll
  for (int h = 0; h < 8; ++h) atomicMax(mb + h, fenc(lrelu(sc[h])));
}

// ---- segment sum of exp(e - max) over dst (per head) ----
__global__ void __launch_bounds__(NT)
edge_sum_kernel(const int* __restrict__ src, const int* __restrict__ dst,
                const float* __restrict__ a, const unsigned* __restrict__ maxb,
                float* __restrict__ denom, int E) {
  int e = blockIdx.x * NT + threadIdx.x;
  if (e >= E) return;
  int s = src[e], d = dst[e];
  const float4* pl = (const float4*)(a + s * 16);
  const float4* pr = (const float4*)(a + d * 16 + 8);
  float4 l0 = pl[0], l1 = pl[1];
  float4 r0 = pr[0], r1 = pr[1];
  float sc[8] = {l0.x + r0.x, l0.y + r0.y, l0.z + r0.z, l0.w + r0.w,
                 l1.x + r1.x, l1.y + r1.y, l1.z + r1.z, l1.w + r1.w};
  const uint4* pm = (const uint4*)(maxb + d * 8);
  uint4 m0 = pm[0], m1 = pm[1];
  float mm[8] = {fdec(m0.x), fdec(m0.y), fdec(m0.z), fdec(m0.w),
                 fdec(m1.x), fdec(m1.y), fdec(m1.z), fdec(m1.w)};
  float* dn = denom + d * 8;
#pragma unroll
  for (int h = 0; h < 8; ++h) atomicAdd(dn + h, __expf(lrelu(sc[h]) - mm[h]));
}

// ---- layer1 aggregation: out1[dst, h*8+f] += alpha[h] * xl1[src, h*8+f] ----
__global__ void __launch_bounds__(NT)
edge_aggr1_kernel(const int* __restrict__ src, const int* __restrict__ dst,
                  const float* __restrict__ a, const unsigned* __restrict__ maxb,
                  const float* __restrict__ denom, const float* __restrict__ xl1,
                  float* __restrict__ out1, int E) {
  int e = blockIdx.x * 4 + (threadIdx.x >> 6);
  if (e >= E) return;
  int lane = threadIdx.x & 63;
  int s = src[e], d = dst[e];
  int h = lane >> 3;
  float sc = lrelu(a[s * 16 + h] + a[d * 16 + 8 + h]);
  float p = __expf(sc - fdec(maxb[d * 8 + h]));
  float alpha = p / (denom[d * 8 + h] + 1e-16f);
  atomicAdd(out1 + d * 64 + lane, alpha * xl1[s * 64 + lane]);
}

// ---- layer 2 GEMM: xl2 = relu(out1) @ W2  ([N,64]@[64,512]) ----
__global__ void __launch_bounds__(NT)
gemm2_kernel(const float* __restrict__ hpre, const float* __restrict__ W2,
             float* __restrict__ xl2, int N) {
  __shared__ float hs[16][64];
  int row0 = blockIdx.x * 16;
  for (int i = threadIdx.x; i < 16 * 64; i += NT) {
    int r = row0 + (i >> 6);
    float v = (r < N) ? hpre[r * 64 + (i & 63)] : 0.f;
    hs[i >> 6][i & 63] = v > 0.f ? v : 0.f;
  }
  __syncthreads();
  int j = threadIdx.x;
  float acc0[16], acc1[16];
#pragma unroll
  for (int r = 0; r < 16; ++r) { acc0[r] = 0.f; acc1[r] = 0.f; }
  for (int k = 0; k < 64; k += 4) {
    float w0[4], w1[4];
#pragma unroll
    for (int kk = 0; kk < 4; ++kk) {
      w0[kk] = W2[(k + kk) * 512 + j];
      w1[kk] = W2[(k + kk) * 512 + j + 256];
    }
#pragma unroll
    for (int r = 0; r < 16; ++r) {
      float4 h4 = *(const float4*)&hs[r][k];
      acc0[r] += h4.x * w0[0] + h4.y * w0[1] + h4.z * w0[2] + h4.w * w0[3];
      acc1[r] += h4.x * w1[0] + h4.y * w1[1] + h4.z * w1[2] + h4.w * w1[3];
    }
  }
#pragma unroll
  for (int r = 0; r < 16; ++r) {
    int n = row0 + r;
    if (n < N) {
      xl2[n * 512 + j] = acc0[r];
      xl2[n * 512 + j + 256] = acc1[r];
    }
  }
}

// ---- layer2 attention dots ----
__global__ void __launch_bounds__(NT)
a2_kernel(const float* __restrict__ xl2, const float* __restrict__ attl,
          const float* __restrict__ attr, float* __restrict__ a2, int N) {
  int n = blockIdx.x * 4 + (threadIdx.x >> 6);
  if (n >= N) return;
  int lane = threadIdx.x & 63;
#pragma unroll
  for (int h = 0; h < 8; ++h) {
    float v = xl2[n * 512 + h * 64 + lane];
    float pl = v * attl[h * 64 + lane];
    float pr = v * attr[h * 64 + lane];
#pragma unroll
    for (int m = 1; m < 64; m <<= 1) {
      pl += __shfl_xor(pl, m, 64);
      pr += __shfl_xor(pr, m, 64);
    }
    if (lane == 0) {
      a2[n * 16 + h] = pl;
      a2[n * 16 + 8 + h] = pr;
    }
  }
}

// ---- layer2 aggregation with fused head-mean:
//      dout[dst,f] += (1/8) * sum_h alpha[h] * xl2[src, h*64+f] ----
__global__ void __launch_bounds__(NT)
edge_aggr2_kernel(const int* __restrict__ src, const int* __restrict__ dst,
                  const float* __restrict__ a, const unsigned* __restrict__ maxb,
                  const float* __restrict__ denom, const float* __restrict__ xl2,
                  float* __restrict__ dout, int E) {
  int e = blockIdx.x * 4 + (threadIdx.x >> 6);
  if (e >= E) return;
  int lane = threadIdx.x & 63;
  int s = src[e], d = dst[e];
  float alpha_own = 0.f;
  if (lane < 8) {
    float sc = lrelu(a[s * 16 + lane] + a[d * 16 + 8 + lane]);
    float p = __expf(sc - fdec(maxb[d * 8 + lane]));
    alpha_own = p / (denom[d * 8 + lane] + 1e-16f);
  }
  float acc = 0.f;
  const float* xr = xl2 + s * 512;
#pragma unroll
  for (int h = 0; h < 8; ++h) {
    float ah = __shfl(alpha_own, h, 64);
    acc += ah * xr[h * 64 + lane];
  }
  atomicAdd(dout + d * 64 + lane, acc * 0.125f);
}

extern "C" void kernel_launch(void* const* d_in, const int* in_sizes, int n_in,
                              void* d_out, int out_size, void* d_ws, size_t ws_size,
                              hipStream_t stream) {
  const float* x     = (const float*)d_in[0];
  const void*  ei    = d_in[1];
  const float* W1    = (const float*)d_in[2];
  const float* attl1 = (const float*)d_in[3];
  const float* attr1 = (const float*)d_in[4];
  const float* b1    = (const float*)d_in[5];
  const float* W2    = (const float*)d_in[6];
  const float* attl2 = (const float*)d_in[7];
  const float* attr2 = (const float*)d_in[8];
  const float* b2    = (const float*)d_in[9];
  float* out = (float*)d_out;

  int N = in_sizes[0] / 128;
  int E = in_sizes[1] / 2;

  char* ws = (char*)d_ws;
  size_t off = 0;
  auto alloc = [&](size_t bytes) {
    char* p = ws + off;
    off += (bytes + 255) & ~size_t(255);
    return p;
  };
  float*    xl1   = (float*)alloc((size_t)N * 64 * 4);
  float*    a1    = (float*)alloc((size_t)N * 16 * 4);
  float*    out1  = (float*)alloc((size_t)N * 64 * 4);
  unsigned* maxb  = (unsigned*)alloc((size_t)N * 8 * 4);
  float*    denom = (float*)alloc((size_t)N * 8 * 4);
  float*    a2    = (float*)alloc((size_t)N * 16 * 4);
  int*      edges = (int*)alloc((size_t)2 * E * 4);
  int*      flag  = (int*)alloc(256);
  float*    xl2   = (float*)alloc((size_t)N * 512 * 4);
  (void)ws_size;

  const int* srcp = edges;
  const int* dstp = edges + E;

  detect_kernel<<<1, NT, 0, stream>>>((const int*)ei, flag, 2 * E);
  cvt_edges_kernel<<<(2 * E + NT - 1) / NT, NT, 0, stream>>>(ei, edges, flag, 2 * E);

  // layer 1
  gemm1_kernel<<<(N + 3) / 4, NT, 0, stream>>>(x, W1, attl1, attr1, xl1, a1, N);
  init_kernel<<<(N * 64 + NT - 1) / NT, NT, 0, stream>>>(out1, b1, maxb, denom, N);
  edge_max_kernel<<<(E + NT - 1) / NT, NT, 0, stream>>>(srcp, dstp, a1, maxb, E);
  edge_sum_kernel<<<(E + NT - 1) / NT, NT, 0, stream>>>(srcp, dstp, a1, maxb, denom, E);
  edge_aggr1_kernel<<<(E + 3) / 4, NT, 0, stream>>>(srcp, dstp, a1, maxb, denom, xl1, out1, E);

  // layer 2
  gemm2_kernel<<<(N + 15) / 16, NT, 0, stream>>>(out1, W2, xl2, N);
  a2_kernel<<<(N + 3) / 4, NT, 0, stream>>>(xl2, attl2, attr2, a2, N);
  init_kernel<<<(N * 64 + NT - 1) / NT, NT, 0, stream>>>(out, b2, maxb, denom, N);
  edge_max_kernel<<<(E + NT - 1) / NT, NT, 0, stream>>>(srcp, dstp, a2, maxb, E);
  edge_sum_kernel<<<(E + NT - 1) / NT, NT, 0, stream>>>(srcp, dstp, a2, maxb, denom, E);
  edge_aggr2_kernel<<<(E + 3) / 4, NT, 0, stream>>>(srcp, dstp, a2, maxb, denom, xl2, out, E);
}

// Round 2
// 621.377 us; speedup vs baseline: 2.9589x; 2.9589x over previous
//
#include <hip/hip_runtime.h>
#include <stdint.h>

#define NT 256

__device__ __forceinline__ float lrelu(float x) { return x > 0.f ? x : 0.2f * x; }

// ---- edge dtype detection (int32 vs int64) + conversion ----
__global__ void detect_kernel(const int* __restrict__ ei, int* __restrict__ flag, int twoE) {
  __shared__ int any;
  if (threadIdx.x == 0) any = 0;
  __syncthreads();
  int n = twoE < 4096 ? twoE : 4096;
  for (int i = threadIdx.x * 2 + 1; i < n; i += 2 * NT)
    if (ei[i] != 0) any = 1;   // benign race, same value
  __syncthreads();
  if (threadIdx.x == 0) *flag = any;   // 1 -> int32 data, 0 -> int64
}

__global__ void cvt_edges_kernel(const void* __restrict__ ei, int* __restrict__ out,
                                 const int* __restrict__ flag, int twoE) {
  int i = blockIdx.x * NT + threadIdx.x;
  if (i >= twoE) return;
  if (*flag) out[i] = ((const int*)ei)[i];
  else       out[i] = (int)((const long long*)ei)[i];
}

// ---- CSR build ----
__global__ void zero2_kernel(int* __restrict__ a, int* __restrict__ b, int n) {
  int i = blockIdx.x * NT + threadIdx.x;
  if (i < n) { a[i] = 0; b[i] = 0; }
}

__global__ void hist_kernel(const int* __restrict__ dst, int* __restrict__ deg, int E) {
  int e = blockIdx.x * NT + threadIdx.x;
  if (e < E) atomicAdd(&deg[dst[e]], 1);
}

__global__ void scan1_kernel(const int* __restrict__ deg, int* __restrict__ bsum, int N) {
  __shared__ int sm[NT];
  int idx = blockIdx.x * NT + threadIdx.x;
  sm[threadIdx.x] = (idx < N) ? deg[idx] : 0;
  __syncthreads();
  for (int s = NT / 2; s > 0; s >>= 1) {
    if (threadIdx.x < s) sm[threadIdx.x] += sm[threadIdx.x + s];
    __syncthreads();
  }
  if (threadIdx.x == 0) bsum[blockIdx.x] = sm[0];
}

__global__ void scan2_kernel(const int* __restrict__ bsum, int* __restrict__ boff, int SB) {
  __shared__ int sm[NT];
  int t = threadIdx.x;
  int v = (t < SB) ? bsum[t] : 0;
  sm[t] = v;
  __syncthreads();
  for (int s = 1; s < NT; s <<= 1) {
    int add = (t >= s) ? sm[t - s] : 0;
    __syncthreads();
    sm[t] += add;
    __syncthreads();
  }
  if (t < SB) boff[t] = sm[t] - v;   // exclusive
}

__global__ void scan3_kernel(const int* __restrict__ deg, const int* __restrict__ boff,
                             int* __restrict__ rowptr, int N) {
  __shared__ int sm[NT];
  int idx = blockIdx.x * NT + threadIdx.x;
  int v = (idx < N) ? deg[idx] : 0;
  sm[threadIdx.x] = v;
  __syncthreads();
  for (int s = 1; s < NT; s <<= 1) {
    int add = (threadIdx.x >= s) ? sm[threadIdx.x - s] : 0;
    __syncthreads();
    sm[threadIdx.x] += add;
    __syncthreads();
  }
  if (idx <= N) rowptr[idx] = boff[blockIdx.x] + sm[threadIdx.x] - v;  // exclusive scan
}

__global__ void scatter_kernel(const int* __restrict__ src, const int* __restrict__ dst,
                               const int* __restrict__ rowptr, int* __restrict__ cursor,
                               int* __restrict__ csr_src, int E) {
  int e = blockIdx.x * NT + threadIdx.x;
  if (e >= E) return;
  int d = dst[e];
  int pos = rowptr[d] + atomicAdd(&cursor[d], 1);
  csr_src[pos] = src[e];
}

// ---- layer 1 GEMM + attention dots: xl1 = x@W1, a1 = [a_l | a_r] ----
__global__ void __launch_bounds__(NT)
gemm1_kernel(const float* __restrict__ x, const float* __restrict__ W1,
             const float* __restrict__ attl, const float* __restrict__ attr,
             float* __restrict__ xl1, float* __restrict__ a1, int N) {
  __shared__ float Ws[128 * 64];
  __shared__ float xs[4][128];
  for (int i = threadIdx.x; i < 128 * 64; i += NT) Ws[i] = W1[i];
  int row0 = blockIdx.x * 4;
  for (int i = threadIdx.x; i < 4 * 128; i += NT) {
    int r = row0 + (i >> 7);
    xs[i >> 7][i & 127] = (r < N) ? x[r * 128 + (i & 127)] : 0.f;
  }
  __syncthreads();
  int wave = threadIdx.x >> 6;
  int lane = threadIdx.x & 63;
  float acc = 0.f;
#pragma unroll 8
  for (int k = 0; k < 128; ++k) acc += xs[wave][k] * Ws[k * 64 + lane];
  int n = row0 + wave;
  if (n < N) {
    xl1[n * 64 + lane] = acc;
    float pl = acc * attl[lane];
    float pr = acc * attr[lane];
#pragma unroll
    for (int m = 1; m < 8; m <<= 1) {
      pl += __shfl_xor(pl, m, 64);
      pr += __shfl_xor(pr, m, 64);
    }
    if ((lane & 7) == 0) {
      int h = lane >> 3;
      a1[n * 16 + h] = pl;
      a1[n * 16 + 8 + h] = pr;
    }
  }
}

// ---- fold W2 with att vectors: wl[k][h] = sum_f W2[k, h*64+f]*attl2[h,f] ----
__global__ void foldw_kernel(const float* __restrict__ W2, const float* __restrict__ attl2,
                             const float* __restrict__ attr2, float* __restrict__ wl,
                             float* __restrict__ wr) {
  int t = threadIdx.x;           // 0..511
  int k = t >> 3, h = t & 7;
  float sl = 0.f, sr = 0.f;
  for (int f = 0; f < 64; ++f) {
    float w = W2[k * 512 + h * 64 + f];
    sl += w * attl2[h * 64 + f];
    sr += w * attr2[h * 64 + f];
  }
  wl[k * 8 + h] = sl;
  wr[k * 8 + h] = sr;
}

// ---- WtT[f][h*64+k] = W2[k][h*64+f] * 0.125 ----
__global__ void foldWt_kernel(const float* __restrict__ W2, float* __restrict__ WtT) {
  int idx = blockIdx.x * NT + threadIdx.x;   // over 512*64
  if (idx >= 512 * 64) return;
  int f = idx & 63;
  int hk = idx >> 6;           // h*64+k
  int h = hk >> 6, k = hk & 63;
  WtT[f * 512 + hk] = W2[k * 512 + h * 64 + f] * 0.125f;
}

// ---- layer1 node-parallel softmax + aggregation (one wave per node) ----
__global__ void __launch_bounds__(NT)
node_aggr1_kernel(const int* __restrict__ rowptr, const int* __restrict__ csr_src,
                  const float* __restrict__ a1, const float* __restrict__ xl1,
                  const float* __restrict__ b1, const float* __restrict__ wl,
                  const float* __restrict__ wr, float* __restrict__ hr,
                  float* __restrict__ a2, int N) {
  int n = blockIdx.x * 4 + (threadIdx.x >> 6);
  if (n >= N) return;
  int lane = threadIdx.x & 63;
  int base = rowptr[n];
  int deg = rowptr[n + 1] - base;

  float4 r0 = *(const float4*)(a1 + n * 16 + 8);
  float4 r1 = *(const float4*)(a1 + n * 16 + 12);
  float ar[8] = {r0.x, r0.y, r0.z, r0.w, r1.x, r1.y, r1.z, r1.w};

  float mx[8];
#pragma unroll
  for (int h = 0; h < 8; ++h) mx[h] = -1e30f;
  for (int j = lane; j < deg; j += 64) {
    int s = csr_src[base + j];
    float4 l0 = *(const float4*)(a1 + s * 16);
    float4 l1 = *(const float4*)(a1 + s * 16 + 4);
    float al[8] = {l0.x, l0.y, l0.z, l0.w, l1.x, l1.y, l1.z, l1.w};
#pragma unroll
    for (int h = 0; h < 8; ++h) mx[h] = fmaxf(mx[h], lrelu(al[h] + ar[h]));
  }
#pragma unroll
  for (int m = 1; m < 64; m <<= 1) {
#pragma unroll
    for (int h = 0; h < 8; ++h) mx[h] = fmaxf(mx[h], __shfl_xor(mx[h], m, 64));
  }

  float sm[8];
#pragma unroll
  for (int h = 0; h < 8; ++h) sm[h] = 0.f;
  for (int j = lane; j < deg; j += 64) {
    int s = csr_src[base + j];
    float4 l0 = *(const float4*)(a1 + s * 16);
    float4 l1 = *(const float4*)(a1 + s * 16 + 4);
    float al[8] = {l0.x, l0.y, l0.z, l0.w, l1.x, l1.y, l1.z, l1.w};
#pragma unroll
    for (int h = 0; h < 8; ++h) sm[h] += __expf(lrelu(al[h] + ar[h]) - mx[h]);
  }
#pragma unroll
  for (int m = 1; m < 64; m <<= 1) {
#pragma unroll
    for (int h = 0; h < 8; ++h) sm[h] += __shfl_xor(sm[h], m, 64);
  }
  float rd[8];
#pragma unroll
  for (int h = 0; h < 8; ++h) rd[h] = 1.f / (sm[h] + 1e-16f);

  // feature-parallel accumulation: lane = h*8+f
  int hown = lane >> 3;
  float mxh = mx[0], rdh = rd[0], arh = ar[0];
#pragma unroll
  for (int h2 = 1; h2 < 8; ++h2)
    if (hown == h2) { mxh = mx[h2]; rdh = rd[h2]; arh = ar[h2]; }

  float acc = 0.f;
  for (int j0 = 0; j0 < deg; j0 += 64) {
    int cnt = deg - j0; if (cnt > 64) cnt = 64;
    int sv = (j0 + lane < deg) ? csr_src[base + j0 + lane] : 0;
    for (int j = 0; j < cnt; ++j) {
      int s = __shfl(sv, j, 64);
      float sc = lrelu(a1[s * 16 + hown] + arh);
      float alpha = __expf(sc - mxh) * rdh;
      acc += alpha * xl1[s * 64 + lane];
    }
  }
  float hv = fmaxf(acc + b1[lane], 0.f);   // relu(out1 + b1)
  hr[n * 64 + lane] = hv;

  // layer-2 attention dots: a2l[h] = sum_k hv_k * wl[k][h]
  float tl[8], tr[8];
#pragma unroll
  for (int h2 = 0; h2 < 8; ++h2) { tl[h2] = hv * wl[lane * 8 + h2]; tr[h2] = hv * wr[lane * 8 + h2]; }
#pragma unroll
  for (int m = 1; m < 64; m <<= 1) {
#pragma unroll
    for (int h2 = 0; h2 < 8; ++h2) { tl[h2] += __shfl_xor(tl[h2], m, 64); tr[h2] += __shfl_xor(tr[h2], m, 64); }
  }
  if (lane == 0) {
#pragma unroll
    for (int h2 = 0; h2 < 8; ++h2) {
      a2[n * 16 + h2] = tl[h2];
      a2[n * 16 + 8 + h2] = tr[h2];
    }
  }
}

// ---- layer2 node-parallel softmax + aggregation of hr into g[n,h,k] ----
__global__ void __launch_bounds__(NT)
node_aggr2_kernel(const int* __restrict__ rowptr, const int* __restrict__ csr_src,
                  const float* __restrict__ a2, const float* __restrict__ hr,
                  float* __restrict__ g, int N) {
  int n = blockIdx.x * 4 + (threadIdx.x >> 6);
  if (n >= N) return;
  int lane = threadIdx.x & 63;
  int base = rowptr[n];
  int deg = rowptr[n + 1] - base;

  float4 r0 = *(const float4*)(a2 + n * 16 + 8);
  float4 r1 = *(const float4*)(a2 + n * 16 + 12);
  float ar[8] = {r0.x, r0.y, r0.z, r0.w, r1.x, r1.y, r1.z, r1.w};

  float mx[8];
#pragma unroll
  for (int h = 0; h < 8; ++h) mx[h] = -1e30f;
  for (int j = lane; j < deg; j += 64) {
    int s = csr_src[base + j];
    float4 l0 = *(const float4*)(a2 + s * 16);
    float4 l1 = *(const float4*)(a2 + s * 16 + 4);
    float al[8] = {l0.x, l0.y, l0.z, l0.w, l1.x, l1.y, l1.z, l1.w};
#pragma unroll
    for (int h = 0; h < 8; ++h) mx[h] = fmaxf(mx[h], lrelu(al[h] + ar[h]));
  }
#pragma unroll
  for (int m = 1; m < 64; m <<= 1) {
#pragma unroll
    for (int h = 0; h < 8; ++h) mx[h] = fmaxf(mx[h], __shfl_xor(mx[h], m, 64));
  }

  float sm[8];
#pragma unroll
  for (int h = 0; h < 8; ++h) sm[h] = 0.f;
  for (int j = lane; j < deg; j += 64) {
    int s = csr_src[base + j];
    float4 l0 = *(const float4*)(a2 + s * 16);
    float4 l1 = *(const float4*)(a2 + s * 16 + 4);
    float al[8] = {l0.x, l0.y, l0.z, l0.w, l1.x, l1.y, l1.z, l1.w};
#pragma unroll
    for (int h = 0; h < 8; ++h) sm[h] += __expf(lrelu(al[h] + ar[h]) - mx[h]);
  }
#pragma unroll
  for (int m = 1; m < 64; m <<= 1) {
#pragma unroll
    for (int h = 0; h < 8; ++h) sm[h] += __shfl_xor(sm[h], m, 64);
  }
  float rd[8];
#pragma unroll
  for (int h = 0; h < 8; ++h) rd[h] = 1.f / (sm[h] + 1e-16f);

  float acc[8];
#pragma unroll
  for (int h = 0; h < 8; ++h) acc[h] = 0.f;
  for (int j0 = 0; j0 < deg; j0 += 64) {
    int cnt = deg - j0; if (cnt > 64) cnt = 64;
    int sv = (j0 + lane < deg) ? csr_src[base + j0 + lane] : 0;
    for (int j = 0; j < cnt; ++j) {
      int s = __shfl(sv, j, 64);
      float4 l0 = *(const float4*)(a2 + s * 16);
      float4 l1 = *(const float4*)(a2 + s * 16 + 4);
      float al[8] = {l0.x, l0.y, l0.z, l0.w, l1.x, l1.y, l1.z, l1.w};
      float hv = hr[s * 64 + lane];
#pragma unroll
      for (int h = 0; h < 8; ++h) {
        float alpha = __expf(lrelu(al[h] + ar[h]) - mx[h]) * rd[h];
        acc[h] += alpha * hv;
      }
    }
  }
#pragma unroll
  for (int h = 0; h < 8; ++h) g[(size_t)n * 512 + h * 64 + lane] = acc[h];
}

// ---- final GEMM: out[N,64] = g[N,512] @ WtT^T + b2 ----
__global__ void __launch_bounds__(NT)
gemm3_kernel(const float* __restrict__ g, const float* __restrict__ WtT,
             const float* __restrict__ b2, float* __restrict__ out, int N) {
  __shared__ float gs[16][512];
  int row0 = blockIdx.x * 16;
  for (int i = threadIdx.x; i < 16 * 128; i += NT) {   // float4 units
    int r = i >> 7, c4 = i & 127;
    int n = row0 + r;
    float4 v = make_float4(0.f, 0.f, 0.f, 0.f);
    if (n < N) v = *(const float4*)(g + (size_t)n * 512 + c4 * 4);
    *(float4*)&gs[r][c4 * 4] = v;
  }
  __syncthreads();
  int col = threadIdx.x & 63;
  int rg = threadIdx.x >> 6;   // 0..3
  float acc[4] = {0.f, 0.f, 0.f, 0.f};
  const float4* wt = (const float4*)(WtT + col * 512);
#pragma unroll 4
  for (int k4 = 0; k4 < 128; ++k4) {
    float4 w = wt[k4];
#pragma unroll
    for (int rr = 0; rr < 4; ++rr) {
      float4 gv = *(const float4*)&gs[rg * 4 + rr][k4 * 4];
      acc[rr] += gv.x * w.x + gv.y * w.y + gv.z * w.z + gv.w * w.w;
    }
  }
  float bb = b2[col];
#pragma unroll
  for (int rr = 0; rr < 4; ++rr) {
    int n = row0 + rg * 4 + rr;
    if (n < N) out[n * 64 + col] = acc[rr] + bb;
  }
}

extern "C" void kernel_launch(void* const* d_in, const int* in_sizes, int n_in,
                              void* d_out, int out_size, void* d_ws, size_t ws_size,
                              hipStream_t stream) {
  const float* x     = (const float*)d_in[0];
  const void*  ei    = d_in[1];
  const float* W1    = (const float*)d_in[2];
  const float* attl1 = (const float*)d_in[3];
  const float* attr1 = (const float*)d_in[4];
  const float* b1    = (const float*)d_in[5];
  const float* W2    = (const float*)d_in[6];
  const float* attl2 = (const float*)d_in[7];
  const float* attr2 = (const float*)d_in[8];
  const float* b2    = (const float*)d_in[9];
  float* out = (float*)d_out;

  int N = in_sizes[0] / 128;
  int E = in_sizes[1] / 2;

  char* ws = (char*)d_ws;
  size_t off = 0;
  auto alloc = [&](size_t bytes) {
    char* p = ws + off;
    off += (bytes + 255) & ~size_t(255);
    return p;
  };
  int*   edges   = (int*)alloc((size_t)2 * E * 4);
  int*   flag    = (int*)alloc(256);
  int*   deg     = (int*)alloc((size_t)N * 4);
  int*   cursor  = (int*)alloc((size_t)N * 4);
  int*   rowptr  = (int*)alloc((size_t)(N + 1) * 4);
  int*   bsum    = (int*)alloc(1024);
  int*   boff    = (int*)alloc(1024);
  int*   csr_src = (int*)alloc((size_t)E * 4);
  float* xl1     = (float*)alloc((size_t)N * 64 * 4);
  float* a1      = (float*)alloc((size_t)N * 16 * 4);
  float* hr      = (float*)alloc((size_t)N * 64 * 4);
  float* a2      = (float*)alloc((size_t)N * 16 * 4);
  float* wl      = (float*)alloc(64 * 8 * 4);
  float* wr      = (float*)alloc(64 * 8 * 4);
  float* WtT     = (float*)alloc(512 * 64 * 4);
  float* g       = (float*)alloc((size_t)N * 512 * 4);
  (void)ws_size;

  const int* srcp = edges;
  const int* dstp = edges + E;
  int SB = (N + 1 + NT - 1) / NT;   // blocks covering N+1 entries (<=256 required)

  detect_kernel<<<1, NT, 0, stream>>>((const int*)ei, flag, 2 * E);
  cvt_edges_kernel<<<(2 * E + NT - 1) / NT, NT, 0, stream>>>(ei, edges, flag, 2 * E);

  // CSR build
  zero2_kernel<<<(N + NT - 1) / NT, NT, 0, stream>>>(deg, cursor, N);
  hist_kernel<<<(E + NT - 1) / NT, NT, 0, stream>>>(dstp, deg, E);
  scan1_kernel<<<SB, NT, 0, stream>>>(deg, bsum, N);
  scan2_kernel<<<1, NT, 0, stream>>>(bsum, boff, SB);
  scan3_kernel<<<SB, NT, 0, stream>>>(deg, boff, rowptr, N);
  scatter_kernel<<<(E + NT - 1) / NT, NT, 0, stream>>>(srcp, dstp, rowptr, cursor, csr_src, E);

  // layer 1 dense part
  gemm1_kernel<<<(N + 3) / 4, NT, 0, stream>>>(x, W1, attl1, attr1, xl1, a1, N);
  foldw_kernel<<<1, 512, 0, stream>>>(W2, attl2, attr2, wl, wr);
  foldWt_kernel<<<(512 * 64 + NT - 1) / NT, NT, 0, stream>>>(W2, WtT);

  // layer 1 aggregation (+ fused layer-2 attention dots)
  node_aggr1_kernel<<<(N + 3) / 4, NT, 0, stream>>>(rowptr, csr_src, a1, xl1, b1, wl, wr, hr, a2, N);

  // layer 2 aggregation of hr into g, then dense transform
  node_aggr2_kernel<<<(N + 3) / 4, NT, 0, stream>>>(rowptr, csr_src, a2, hr, g, N);
  gemm3_kernel<<<(N + 15) / 16, NT, 0, stream>>>(g, WtT, b2, out, N);
}

// Round 3
// 456.132 us; speedup vs baseline: 4.0308x; 1.3623x over previous
//
#include <hip/hip_runtime.h>
#include <stdint.h>

#define NT 256

__device__ __forceinline__ float lrelu(float x) { return x > 0.f ? x : 0.2f * x; }

// ---- edge dtype detection (int32 vs int64) + conversion ----
__global__ void detect_kernel(const int* __restrict__ ei, int* __restrict__ flag, int twoE) {
  __shared__ int any;
  if (threadIdx.x == 0) any = 0;
  __syncthreads();
  int n = twoE < 4096 ? twoE : 4096;
  for (int i = threadIdx.x * 2 + 1; i < n; i += 2 * NT)
    if (ei[i] != 0) any = 1;   // benign race, same value
  __syncthreads();
  if (threadIdx.x == 0) *flag = any;   // 1 -> int32 data, 0 -> int64
}

__global__ void cvt_edges_kernel(const void* __restrict__ ei, int* __restrict__ out,
                                 const int* __restrict__ flag, int twoE) {
  int i = blockIdx.x * NT + threadIdx.x;
  if (i >= twoE) return;
  if (*flag) out[i] = ((const int*)ei)[i];
  else       out[i] = (int)((const long long*)ei)[i];
}

// ---- CSR build ----
__global__ void zero2_kernel(int* __restrict__ a, int* __restrict__ b, int n) {
  int i = blockIdx.x * NT + threadIdx.x;
  if (i < n) { a[i] = 0; b[i] = 0; }
}

__global__ void hist_kernel(const int* __restrict__ dst, int* __restrict__ deg, int E) {
  int e = blockIdx.x * NT + threadIdx.x;
  if (e < E) atomicAdd(&deg[dst[e]], 1);
}

__global__ void scan1_kernel(const int* __restrict__ deg, int* __restrict__ bsum, int N) {
  __shared__ int sm[NT];
  int idx = blockIdx.x * NT + threadIdx.x;
  sm[threadIdx.x] = (idx < N) ? deg[idx] : 0;
  __syncthreads();
  for (int s = NT / 2; s > 0; s >>= 1) {
    if (threadIdx.x < s) sm[threadIdx.x] += sm[threadIdx.x + s];
    __syncthreads();
  }
  if (threadIdx.x == 0) bsum[blockIdx.x] = sm[0];
}

__global__ void scan2_kernel(const int* __restrict__ bsum, int* __restrict__ boff, int SB) {
  __shared__ int sm[NT];
  int t = threadIdx.x;
  int v = (t < SB) ? bsum[t] : 0;
  sm[t] = v;
  __syncthreads();
  for (int s = 1; s < NT; s <<= 1) {
    int add = (t >= s) ? sm[t - s] : 0;
    __syncthreads();
    sm[t] += add;
    __syncthreads();
  }
  if (t < SB) boff[t] = sm[t] - v;   // exclusive
}

__global__ void scan3_kernel(const int* __restrict__ deg, const int* __restrict__ boff,
                             int* __restrict__ rowptr, int N) {
  __shared__ int sm[NT];
  int idx = blockIdx.x * NT + threadIdx.x;
  int v = (idx < N) ? deg[idx] : 0;
  sm[threadIdx.x] = v;
  __syncthreads();
  for (int s = 1; s < NT; s <<= 1) {
    int add = (threadIdx.x >= s) ? sm[threadIdx.x - s] : 0;
    __syncthreads();
    sm[threadIdx.x] += add;
    __syncthreads();
  }
  if (idx <= N) rowptr[idx] = boff[blockIdx.x] + sm[threadIdx.x] - v;  // exclusive scan
}

__global__ void scatter_kernel(const int* __restrict__ src, const int* __restrict__ dst,
                               const int* __restrict__ rowptr, int* __restrict__ cursor,
                               int* __restrict__ csr_src, int E) {
  int e = blockIdx.x * NT + threadIdx.x;
  if (e >= E) return;
  int d = dst[e];
  int pos = rowptr[d] + atomicAdd(&cursor[d], 1);
  csr_src[pos] = src[e];
}

// ---- layer 1 GEMM + attention dots: xl1 = x@W1, a1 = [a_l | a_r] ----
__global__ void __launch_bounds__(NT)
gemm1_kernel(const float* __restrict__ x, const float* __restrict__ W1,
             const float* __restrict__ attl, const float* __restrict__ attr,
             float* __restrict__ xl1, float* __restrict__ a1, int N) {
  __shared__ float Ws[128 * 64];
  __shared__ float xs[4][128];
  for (int i = threadIdx.x; i < 128 * 64; i += NT) Ws[i] = W1[i];
  int row0 = blockIdx.x * 4;
  for (int i = threadIdx.x; i < 4 * 128; i += NT) {
    int r = row0 + (i >> 7);
    xs[i >> 7][i & 127] = (r < N) ? x[r * 128 + (i & 127)] : 0.f;
  }
  __syncthreads();
  int wave = threadIdx.x >> 6;
  int lane = threadIdx.x & 63;
  float acc = 0.f;
#pragma unroll 8
  for (int k = 0; k < 128; ++k) acc += xs[wave][k] * Ws[k * 64 + lane];
  int n = row0 + wave;
  if (n < N) {
    xl1[n * 64 + lane] = acc;
    float pl = acc * attl[lane];
    float pr = acc * attr[lane];
#pragma unroll
    for (int m = 1; m < 8; m <<= 1) {
      pl += __shfl_xor(pl, m, 64);
      pr += __shfl_xor(pr, m, 64);
    }
    if ((lane & 7) == 0) {
      int h = lane >> 3;
      a1[n * 16 + h] = pl;
      a1[n * 16 + 8 + h] = pr;
    }
  }
}

// ---- fold W2 with att vectors: wl[k][h] = sum_f W2[k, h*64+f]*attl2[h,f] ----
__global__ void foldw_kernel(const float* __restrict__ W2, const float* __restrict__ attl2,
                             const float* __restrict__ attr2, float* __restrict__ wl,
                             float* __restrict__ wr) {
  int t = threadIdx.x;           // 0..511
  int k = t >> 3, h = t & 7;
  float sl = 0.f, sr = 0.f;
  for (int f = 0; f < 64; ++f) {
    float w = W2[k * 512 + h * 64 + f];
    sl += w * attl2[h * 64 + f];
    sr += w * attr2[h * 64 + f];
  }
  wl[k * 8 + h] = sl;
  wr[k * 8 + h] = sr;
}

// ---- Wt2[hk][f] = W2[k, h*64+f] * 0.125  (coalesced over f) ----
__global__ void foldWt_kernel(const float* __restrict__ W2, float* __restrict__ Wt2) {
  int idx = blockIdx.x * NT + threadIdx.x;   // over 512*64
  if (idx >= 512 * 64) return;
  int f = idx & 63;
  int hk = idx >> 6;           // h*64+k
  int h = hk >> 6, k = hk & 63;
  Wt2[idx] = W2[k * 512 + h * 64 + f] * 0.125f;
}

// ---- layer1: single-pass softmax+aggregation, one wave per node ----
// lane = h*8+f  (feature-parallel within head blocks of 8)
__global__ void __launch_bounds__(NT)
node_aggr1_kernel(const int* __restrict__ rowptr, const int* __restrict__ csr_src,
                  const float* __restrict__ a1, const float* __restrict__ xl1,
                  const float* __restrict__ b1, const float* __restrict__ wl,
                  const float* __restrict__ wr, float* __restrict__ hr,
                  float* __restrict__ a2, int N) {
  int n = blockIdx.x * 4 + (threadIdx.x >> 6);
  if (n >= N) return;
  int lane = threadIdx.x & 63;
  int hown = lane >> 3;
  int base = rowptr[n];
  int deg = rowptr[n + 1] - base;

  float arh = a1[n * 16 + 8 + hown];
  float acc = 0.f, dn = 0.f;
  for (int j0 = 0; j0 < deg; j0 += 64) {
    int cnt = deg - j0; if (cnt > 64) cnt = 64;
    int sv = (j0 + lane < deg) ? csr_src[base + j0 + lane] : 0;
    for (int j = 0; j < cnt; ++j) {
      int s = __shfl(sv, j, 64);
      float p = __expf(lrelu(a1[s * 16 + hown] + arh));
      dn += p;
      acc += p * xl1[s * 64 + lane];
    }
  }
  acc = acc / (dn + 1e-16f);
  float hv = fmaxf(acc + b1[lane], 0.f);   // relu(out1 + b1)
  hr[n * 64 + lane] = hv;

  // layer-2 attention dots: a2l[h] = sum_k hv_k * wl[k][h]
  float tl[8], tr[8];
#pragma unroll
  for (int h2 = 0; h2 < 8; ++h2) { tl[h2] = hv * wl[lane * 8 + h2]; tr[h2] = hv * wr[lane * 8 + h2]; }
#pragma unroll
  for (int m = 1; m < 64; m <<= 1) {
#pragma unroll
    for (int h2 = 0; h2 < 8; ++h2) { tl[h2] += __shfl_xor(tl[h2], m, 64); tr[h2] += __shfl_xor(tr[h2], m, 64); }
  }
  if (lane == 0) {
#pragma unroll
    for (int h2 = 0; h2 < 8; ++h2) {
      a2[n * 16 + h2] = tl[h2];
      a2[n * 16 + 8 + h2] = tr[h2];
    }
  }
}

// ---- layer2: single-pass softmax+aggregation + fused W2 epilogue ----
// lane = k (0..63); head owned for score calc: hown = lane&7
__global__ void __launch_bounds__(NT)
node_aggr2_kernel(const int* __restrict__ rowptr, const int* __restrict__ csr_src,
                  const float* __restrict__ a2, const float* __restrict__ hr,
                  const float* __restrict__ Wt2, const float* __restrict__ b2,
                  float* __restrict__ out, int N) {
  __shared__ float gs[4][512];
  int w = threadIdx.x >> 6;
  int n = blockIdx.x * 4 + w;
  int lane = threadIdx.x & 63;
  int hown = lane & 7;
  bool valid = n < N;

  float acc[8];
#pragma unroll
  for (int h = 0; h < 8; ++h) acc[h] = 0.f;
  float dnown = 0.f;

  if (valid) {
    int base = rowptr[n];
    int deg = rowptr[n + 1] - base;
    float arown = a2[n * 16 + 8 + hown];
    for (int j0 = 0; j0 < deg; j0 += 64) {
      int cnt = deg - j0; if (cnt > 64) cnt = 64;
      int sv = (j0 + lane < deg) ? csr_src[base + j0 + lane] : 0;
      for (int j = 0; j < cnt; ++j) {
        int s = __shfl(sv, j, 64);
        float pown = __expf(lrelu(a2[s * 16 + hown] + arown));
        dnown += pown;
        float hv = hr[s * 64 + lane];
#pragma unroll
        for (int h = 0; h < 8; ++h) acc[h] += __shfl(pown, h, 64) * hv;
      }
    }
#pragma unroll
    for (int h = 0; h < 8; ++h) {
      float dnh = __shfl(dnown, h, 64);
      acc[h] *= 1.f / (dnh + 1e-16f);
      gs[w][h * 64 + lane] = acc[h];
    }
  }
  __syncthreads();
  if (valid) {
    // out[n,f] = b2[f] + sum_hk gs[hk] * Wt2[hk*64+f],  f = lane
    float o = 0.f;
#pragma unroll 4
    for (int hk4 = 0; hk4 < 128; ++hk4) {
      float4 gv = *(const float4*)&gs[w][hk4 * 4];
      o += gv.x * Wt2[(hk4 * 4 + 0) * 64 + lane];
      o += gv.y * Wt2[(hk4 * 4 + 1) * 64 + lane];
      o += gv.z * Wt2[(hk4 * 4 + 2) * 64 + lane];
      o += gv.w * Wt2[(hk4 * 4 + 3) * 64 + lane];
    }
    out[n * 64 + lane] = o + b2[lane];
  }
}

extern "C" void kernel_launch(void* const* d_in, const int* in_sizes, int n_in,
                              void* d_out, int out_size, void* d_ws, size_t ws_size,
                              hipStream_t stream) {
  const float* x     = (const float*)d_in[0];
  const void*  ei    = d_in[1];
  const float* W1    = (const float*)d_in[2];
  const float* attl1 = (const float*)d_in[3];
  const float* attr1 = (const float*)d_in[4];
  const float* b1    = (const float*)d_in[5];
  const float* W2    = (const float*)d_in[6];
  const float* attl2 = (const float*)d_in[7];
  const float* attr2 = (const float*)d_in[8];
  const float* b2    = (const float*)d_in[9];
  float* out = (float*)d_out;

  int N = in_sizes[0] / 128;
  int E = in_sizes[1] / 2;

  char* ws = (char*)d_ws;
  size_t off = 0;
  auto alloc = [&](size_t bytes) {
    char* p = ws + off;
    off += (bytes + 255) & ~size_t(255);
    return p;
  };
  int*   edges   = (int*)alloc((size_t)2 * E * 4);
  int*   flag    = (int*)alloc(256);
  int*   deg     = (int*)alloc((size_t)N * 4);
  int*   cursor  = (int*)alloc((size_t)N * 4);
  int*   rowptr  = (int*)alloc((size_t)(N + 1) * 4);
  int*   bsum    = (int*)alloc(1024);
  int*   boff    = (int*)alloc(1024);
  int*   csr_src = (int*)alloc((size_t)E * 4);
  float* xl1     = (float*)alloc((size_t)N * 64 * 4);
  float* a1      = (float*)alloc((size_t)N * 16 * 4);
  float* hr      = (float*)alloc((size_t)N * 64 * 4);
  float* a2      = (float*)alloc((size_t)N * 16 * 4);
  float* wl      = (float*)alloc(64 * 8 * 4);
  float* wr      = (float*)alloc(64 * 8 * 4);
  float* Wt2     = (float*)alloc(512 * 64 * 4);
  (void)ws_size;

  const int* srcp = edges;
  const int* dstp = edges + E;
  int SB = (N + 1 + NT - 1) / NT;   // must be <= 256

  detect_kernel<<<1, NT, 0, stream>>>((const int*)ei, flag, 2 * E);
  cvt_edges_kernel<<<(2 * E + NT - 1) / NT, NT, 0, stream>>>(ei, edges, flag, 2 * E);

  // CSR build
  zero2_kernel<<<(N + NT - 1) / NT, NT, 0, stream>>>(deg, cursor, N);
  hist_kernel<<<(E + NT - 1) / NT, NT, 0, stream>>>(dstp, deg, E);
  scan1_kernel<<<SB, NT, 0, stream>>>(deg, bsum, N);
  scan2_kernel<<<1, NT, 0, stream>>>(bsum, boff, SB);
  scan3_kernel<<<SB, NT, 0, stream>>>(deg, boff, rowptr, N);
  scatter_kernel<<<(E + NT - 1) / NT, NT, 0, stream>>>(srcp, dstp, rowptr, cursor, csr_src, E);

  // dense precomputation
  gemm1_kernel<<<(N + 3) / 4, NT, 0, stream>>>(x, W1, attl1, attr1, xl1, a1, N);
  foldw_kernel<<<1, 512, 0, stream>>>(W2, attl2, attr2, wl, wr);
  foldWt_kernel<<<(512 * 64 + NT - 1) / NT, NT, 0, stream>>>(W2, Wt2);

  // layer 1 aggregation (+ fused relu/bias + layer-2 attention dots)
  node_aggr1_kernel<<<(N + 3) / 4, NT, 0, stream>>>(rowptr, csr_src, a1, xl1, b1, wl, wr, hr, a2, N);

  // layer 2 aggregation + fused W2/mean/bias epilogue
  node_aggr2_kernel<<<(N + 3) / 4, NT, 0, stream>>>(rowptr, csr_src, a2, hr, Wt2, b2, out, N);
}